// Round 7
// baseline (1131.764 us; speedup 1.0000x reference)
//
#include <hip/hip_runtime.h>
#include <cstddef>
#include <cstdint>

typedef __attribute__((ext_vector_type(8))) short bf16x8;
typedef __attribute__((ext_vector_type(4))) float f32x4;
typedef __attribute__((ext_vector_type(2))) float f32x2;
typedef unsigned int u32t;
typedef unsigned short u16t;
typedef unsigned char u8t;

__device__ inline u16t f2bf(float f) {
  union { float f; unsigned u; } c; c.f = f;
  return (u16t)((c.u + 0x7FFFu + ((c.u >> 16) & 1u)) >> 16);
}
__device__ inline float ubits(u32t u) { union { u32t u; float f; } c; c.u = u; return c.f; }
__device__ inline float bf2f(u16t u) { return ubits(((u32t)u) << 16); }
__device__ inline float fsig(float x) { return __builtin_amdgcn_rcpf(1.f + __expf(-x)); }
__device__ inline float ftanh(float x) {
  float t = __expf(-2.f * fabsf(x));
  return copysignf((1.f - t) * __builtin_amdgcn_rcpf(1.f + t), x);
}
__device__ inline u32t f32x4_to_fp8(float a, float b, float c, float d) {
  int v = __builtin_amdgcn_cvt_pk_fp8_f32(a, b, 0, false);
  v = __builtin_amdgcn_cvt_pk_fp8_f32(c, d, v, true);
  return (u32t)v;
}

// bf16 weight mats, row-major [128][128]:
// 0: Wzf  1: Wzh  2: Wr  3: Whf  4: Whh  5: Ur
__global__ __launch_bounds__(256) void conv_weights(
    const float* __restrict__ Wz, const float* __restrict__ Wr,
    const float* __restrict__ Ur, const float* __restrict__ Wh,
    short* __restrict__ out)
{
  int i = blockIdx.x * 256 + threadIdx.x;
  if (i >= 6 * 16384) return;
  int mat = i >> 14, idx = i & 16383;
  int o = idx >> 7, c = idx & 127;
  float v = 0.f;
  switch (mat) {
    case 0: v = Wz[o * 256 + c];        break;
    case 1: v = Wz[o * 256 + 128 + c];  break;
    case 2: v = Wr[o * 128 + c];        break;
    case 3: v = Wh[o * 256 + c];        break;
    case 4: v = Wh[o * 256 + 128 + c];  break;
    case 5: v = Ur[o * 128 + c];        break;
  }
  out[i] = (short)f2bf(v);
}

__global__ __launch_bounds__(256) void conv_fmess(const float* __restrict__ src,
                                                  u16t* __restrict__ dst, size_t n8)
{
  size_t i = (size_t)blockIdx.x * 256 + threadIdx.x;
  if (i >= n8) return;
  const float4 a = *reinterpret_cast<const float4*>(src + i * 8);
  const float4 b = *reinterpret_cast<const float4*>(src + i * 8 + 4);
  uint4 o;
  o.x = ((u32t)f2bf(a.y) << 16) | f2bf(a.x);
  o.y = ((u32t)f2bf(a.w) << 16) | f2bf(a.z);
  o.z = ((u32t)f2bf(b.y) << 16) | f2bf(b.x);
  o.w = ((u32t)f2bf(b.w) << 16) | f2bf(b.z);
  *reinterpret_cast<uint4*>(dst + i * 8) = o;
}

__global__ void detect64(const int* __restrict__ bg, int* __restrict__ flag) {
  int t = threadIdx.x;
  int v = bg[2 * t + 1];
  unsigned long long m = __ballot(v == 0);
  if (t == 0) *flag = (m == ~0ull) ? 1 : 0;
}

__global__ __launch_bounds__(256) void compact_bg(const int* __restrict__ bg,
                                                  const int* __restrict__ flag,
                                                  int* __restrict__ bg32, int n)
{
  int i = blockIdx.x * 256 + threadIdx.x;
  if (i < n) bg32[i] = (*flag) ? bg[2 * (size_t)i] : bg[i];
}

// ---- gather macros: each 32-lane half owns whole rows; no cross-half combine ----
// GLx(q, nbb): load 4 neighbors (nbb..nbb+3) of local row hf*4+q into named regs.
#define GLD(H0, H1, H2, H3, P0, P1, P2, P3, q, nbb) { \
  int i0_ = __shfl(idx_all, (hf * 4 + (q)) * 8 + (nbb) + 0); \
  int i1_ = __shfl(idx_all, (hf * 4 + (q)) * 8 + (nbb) + 1); \
  int i2_ = __shfl(idx_all, (hf * 4 + (q)) * 8 + (nbb) + 2); \
  int i3_ = __shfl(idx_all, (hf * 4 + (q)) * 8 + (nbb) + 3); \
  H0 = *reinterpret_cast<const uint2*>(Hin + (size_t)i0_ * 128 + l5 * 4); \
  H1 = *reinterpret_cast<const uint2*>(Hin + (size_t)i1_ * 128 + l5 * 4); \
  H2 = *reinterpret_cast<const uint2*>(Hin + (size_t)i2_ * 128 + l5 * 4); \
  H3 = *reinterpret_cast<const uint2*>(Hin + (size_t)i3_ * 128 + l5 * 4); \
  P0 = *reinterpret_cast<const u32t*>(Pin + (size_t)i0_ * 128 + l5 * 4); \
  P1 = *reinterpret_cast<const u32t*>(Pin + (size_t)i1_ * 128 + l5 * 4); \
  P2 = *reinterpret_cast<const u32t*>(Pin + (size_t)i2_ * 128 + l5 * 4); \
  P3 = *reinterpret_cast<const u32t*>(Pin + (size_t)i3_ * 128 + l5 * 4); \
}

#define PRN(HV, PW) { \
  f32x2 plo_ = __builtin_amdgcn_cvt_pk_f32_fp8((int)(PW), false); \
  f32x2 phi_ = __builtin_amdgcn_cvt_pk_f32_fp8((int)(PW), true); \
  float h0_ = ubits(HV.x << 16), h1_ = ubits(HV.x & 0xffff0000u); \
  float h2_ = ubits(HV.y << 16), h3_ = ubits(HV.y & 0xffff0000u); \
  s0 += h0_; g0 += fsig(r10 + plo_.x) * h0_; \
  s1 += h1_; g1 += fsig(r11 + plo_.y) * h1_; \
  s2 += h2_; g2 += fsig(r12 + phi_.x) * h2_; \
  s3 += h3_; g3 += fsig(r13 + phi_.y) * h3_; \
}

#define PR4(HH0, HH1, HH2, HH3, PP0, PP1, PP2, PP3) \
  PRN(HH0, PP0) PRN(HH1, PP1) PRN(HH2, PP2) PRN(HH3, PP3)

#define INITR(q) { \
  int rl_ = wave * 8 + hf * 4 + (q); \
  uint2 rp_ = *reinterpret_cast<const uint2*>(s_R1 + rl_ * 136 + l5 * 4); \
  r10 = ubits(rp_.x << 16); r11 = ubits(rp_.x & 0xffff0000u); \
  r12 = ubits(rp_.y << 16); r13 = ubits(rp_.y & 0xffff0000u); \
  s0 = s1 = s2 = s3 = 0.f; g0 = g1 = g2 = g3 = 0.f; \
}

#define FINR(q) { \
  int rl_ = wave * 8 + hf * 4 + (q); \
  uint2 sp_, gp_; \
  sp_.x = ((u32t)f2bf(s1) << 16) | f2bf(s0); \
  sp_.y = ((u32t)f2bf(s3) << 16) | f2bf(s2); \
  gp_.x = ((u32t)f2bf(g1) << 16) | f2bf(g0); \
  gp_.y = ((u32t)f2bf(g3) << 16) | f2bf(g2); \
  *reinterpret_cast<uint2*>(s_sb + rl_ * 136 + l5 * 4) = sp_; \
  *reinterpret_cast<uint2*>(s_gb + rl_ * 136 + l5 * 4) = gp_; \
}

// LDS map (26112 B -> 6 blocks/CU by LDS):
//  [0,8704)      s_fm u16[32][136]; aliased by s_sb after af extraction
//  [8704,17408)  s_R1 u16[32][136]; (with s_gb) aliased by MODE2 fp32 out-stage
//  [17408,26112) s_gb u16[32][136]
template<int MODE>   // 0=first step (h=0), 1=middle, 2=last (fp32 out)
__global__ __launch_bounds__(256, 4) void step_k(
    const u16t* __restrict__ fmb,
    const int*  __restrict__ bg32,
    const u16t* __restrict__ Hin,
    const u8t*  __restrict__ Pin,
    const short* __restrict__ wbf,
    const float* __restrict__ bz, const float* __restrict__ urb, const float* __restrict__ bh,
    u16t* __restrict__ Hout, u8t* __restrict__ Pout, float* __restrict__ houtf, int E)
{
  __shared__ __align__(16) char smem[26112];
  u16t* s_fm = (u16t*)smem;
  u16t* s_sb = (u16t*)smem;
  u16t* s_R1 = (u16t*)(smem + 8704);
  u16t* s_gb = (u16t*)(smem + 17408);

  const int tid = threadIdx.x, wave = tid >> 6, lane = tid & 63;
  const int cl = lane & 15, kg = lane >> 4;
  const int l5 = lane & 31, hf = lane >> 5;
  const int base = blockIdx.x * 32;
  const int mrow = (wave & 1) * 16, ncol = (wave >> 1) * 64;

  // ---- phase 1: fmess tile -> LDS ; neighbor indices -> regs ----
  #pragma unroll
  for (int it = 0; it < 2; ++it) {
    int s = it * 256 + tid;
    int r = s >> 4, c = (s & 15) * 8;
    uint4 v = {0u, 0u, 0u, 0u};
    int e = base + r;
    if (e < E) v = *reinterpret_cast<const uint4*>(fmb + (size_t)e * 128 + c);
    *reinterpret_cast<uint4*>(s_fm + r * 136 + c) = v;
  }
  int idx_all = 0;
  if (MODE != 0) {
    int er = base + wave * 8 + (lane >> 3);
    if (er >= E) er = 0;
    idx_all = bg32[(size_t)er * 8 + (lane & 7)];
  }
  __syncthreads();

  const short* Wzf = wbf;
  const short* Wzh = wbf + 16384;
  const short* Wr  = wbf + 2 * 16384;
  const short* Whf = wbf + 3 * 16384;
  const short* Whh = wbf + 4 * 16384;
  const short* Ur  = wbf + 5 * 16384;

  bf16x8 af[4];
  #pragma unroll
  for (int ks = 0; ks < 4; ++ks)
    af[ks] = *reinterpret_cast<const bf16x8*>(s_fm + (mrow + cl) * 136 + ks * 32 + kg * 8);

  if (MODE != 0) {
    // ---- phase 2: R1 = fmess @ Wr^T + urb -> s_R1 ----
    {
      f32x4 racc[4];
      #pragma unroll
      for (int nt = 0; nt < 4; ++nt) racc[nt] = (f32x4){0.f, 0.f, 0.f, 0.f};
      #pragma unroll
      for (int ks = 0; ks < 4; ++ks) {
        #pragma unroll
        for (int nt = 0; nt < 4; ++nt) {
          bf16x8 b = *reinterpret_cast<const bf16x8*>(Wr + (size_t)(ncol + nt * 16 + cl) * 128 + ks * 32 + kg * 8);
          racc[nt] = __builtin_amdgcn_mfma_f32_16x16x32_bf16(af[ks], b, racc[nt], 0, 0, 0);
        }
      }
      #pragma unroll
      for (int nt = 0; nt < 4; ++nt) {
        int n = ncol + nt * 16 + cl;
        float bias = urb[n];
        #pragma unroll
        for (int r = 0; r < 4; ++r)
          s_R1[(mrow + kg * 4 + r) * 136 + n] = f2bf(racc[nt][r] + bias);
      }
    }
    __syncthreads();   // s_R1 visible; af in regs -> s_fm region (s_sb) reusable

    // ---- phase 3: gather, 2-deep pipeline, half-wave owns rows ----
    uint2 HA0, HA1, HA2, HA3, HB0, HB1, HB2, HB3;
    u32t  PA0, PA1, PA2, PA3, PB0, PB1, PB2, PB3;
    float s0, s1, s2, s3, g0, g1, g2, g3, r10, r11, r12, r13;

    GLD(HA0, HA1, HA2, HA3, PA0, PA1, PA2, PA3, 0, 0)
    GLD(HB0, HB1, HB2, HB3, PB0, PB1, PB2, PB3, 0, 4)
    INITR(0)
    PR4(HA0, HA1, HA2, HA3, PA0, PA1, PA2, PA3)
    GLD(HA0, HA1, HA2, HA3, PA0, PA1, PA2, PA3, 1, 0)
    PR4(HB0, HB1, HB2, HB3, PB0, PB1, PB2, PB3)
    FINR(0)
    GLD(HB0, HB1, HB2, HB3, PB0, PB1, PB2, PB3, 1, 4)
    INITR(1)
    PR4(HA0, HA1, HA2, HA3, PA0, PA1, PA2, PA3)
    GLD(HA0, HA1, HA2, HA3, PA0, PA1, PA2, PA3, 2, 0)
    PR4(HB0, HB1, HB2, HB3, PB0, PB1, PB2, PB3)
    FINR(1)
    GLD(HB0, HB1, HB2, HB3, PB0, PB1, PB2, PB3, 2, 4)
    INITR(2)
    PR4(HA0, HA1, HA2, HA3, PA0, PA1, PA2, PA3)
    GLD(HA0, HA1, HA2, HA3, PA0, PA1, PA2, PA3, 3, 0)
    PR4(HB0, HB1, HB2, HB3, PB0, PB1, PB2, PB3)
    FINR(2)
    GLD(HB0, HB1, HB2, HB3, PB0, PB1, PB2, PB3, 3, 4)
    INITR(3)
    PR4(HA0, HA1, HA2, HA3, PA0, PA1, PA2, PA3)
    PR4(HB0, HB1, HB2, HB3, PB0, PB1, PB2, PB3)
    FINR(3)
    __syncthreads();   // s_sb/s_gb complete
  }

  // ---- phase 4a: z = sigmoid(Wzf·fm + Wzh·sum + bz) ----
  float zv[4][4];
  {
    f32x4 t0[4], t1[4];
    #pragma unroll
    for (int nt = 0; nt < 4; ++nt) { t0[nt] = (f32x4){0.f, 0.f, 0.f, 0.f}; t1[nt] = (f32x4){0.f, 0.f, 0.f, 0.f}; }
    #pragma unroll
    for (int ks = 0; ks < 4; ++ks) {
      #pragma unroll
      for (int nt = 0; nt < 4; ++nt) {
        int n = ncol + nt * 16 + cl;
        bf16x8 b1 = *reinterpret_cast<const bf16x8*>(Wzf + (size_t)n * 128 + ks * 32 + kg * 8);
        t0[nt] = __builtin_amdgcn_mfma_f32_16x16x32_bf16(af[ks], b1, t0[nt], 0, 0, 0);
        if (MODE != 0) {
          bf16x8 az = *reinterpret_cast<const bf16x8*>(s_sb + (mrow + cl) * 136 + ks * 32 + kg * 8);
          bf16x8 b2 = *reinterpret_cast<const bf16x8*>(Wzh + (size_t)n * 128 + ks * 32 + kg * 8);
          t1[nt] = __builtin_amdgcn_mfma_f32_16x16x32_bf16(az, b2, t1[nt], 0, 0, 0);
        }
      }
    }
    #pragma unroll
    for (int nt = 0; nt < 4; ++nt) {
      int n = ncol + nt * 16 + cl;
      float bzv = bz[n];
      #pragma unroll
      for (int r = 0; r < 4; ++r)
        zv[nt][r] = fsig(t0[nt][r] + t1[nt][r] + bzv);
    }
  }

  // ---- phase 4b: pre = tanh(Whf·fm + Whh·gated + bh) ; epilogue ----
  float nh_sv[4][4];
  {
    f32x4 t0[4], t1[4];
    #pragma unroll
    for (int nt = 0; nt < 4; ++nt) { t0[nt] = (f32x4){0.f, 0.f, 0.f, 0.f}; t1[nt] = (f32x4){0.f, 0.f, 0.f, 0.f}; }
    #pragma unroll
    for (int ks = 0; ks < 4; ++ks) {
      #pragma unroll
      for (int nt = 0; nt < 4; ++nt) {
        int n = ncol + nt * 16 + cl;
        bf16x8 b1 = *reinterpret_cast<const bf16x8*>(Whf + (size_t)n * 128 + ks * 32 + kg * 8);
        t0[nt] = __builtin_amdgcn_mfma_f32_16x16x32_bf16(af[ks], b1, t0[nt], 0, 0, 0);
        if (MODE != 0) {
          bf16x8 ag = *reinterpret_cast<const bf16x8*>(s_gb + (mrow + cl) * 136 + ks * 32 + kg * 8);
          bf16x8 b2 = *reinterpret_cast<const bf16x8*>(Whh + (size_t)n * 128 + ks * 32 + kg * 8);
          t1[nt] = __builtin_amdgcn_mfma_f32_16x16x32_bf16(ag, b2, t1[nt], 0, 0, 0);
        }
      }
    }
    #pragma unroll
    for (int nt = 0; nt < 4; ++nt) {
      int n = ncol + nt * 16 + cl;
      float bhv = bh[n];
      #pragma unroll
      for (int r = 0; r < 4; ++r) {
        int rowt = mrow + kg * 4 + r;
        int e = base + rowt;
        float pre = ftanh(t0[nt][r] + t1[nt][r] + bhv);
        float sh  = (MODE == 0) ? 0.f : bf2f(s_sb[rowt * 136 + n]);
        float z   = zv[nt][r];
        float nh  = (1.f - z) * sh + z * pre;
        if (e == 0) nh = 0.f;
        nh_sv[nt][r] = nh;
      }
    }
  }

  // ---- phase 6 ----
  if (MODE == 2) {
    __syncthreads();
    float* so = (float*)(smem + 8704);   // 16 KB stage over s_R1+s_gb
    #pragma unroll
    for (int nt = 0; nt < 4; ++nt) {
      int n = ncol + nt * 16 + cl;
      #pragma unroll
      for (int r = 0; r < 4; ++r)
        so[(mrow + kg * 4 + r) * 128 + n] = nh_sv[nt][r];
    }
    __syncthreads();
    #pragma unroll
    for (int it = 0; it < 4; ++it) {
      int slot = it * 256 + tid;
      int row = slot >> 5, seg = slot & 31;
      if (base + row < E)
        *reinterpret_cast<float4*>(houtf + (size_t)(base + row) * 128 + seg * 4) =
            *reinterpret_cast<const float4*>(so + row * 128 + seg * 4);
    }
  } else {
    // stage h_next -> s_sb, P_next = h_next @ Ur^T -> s_gb (bf16), then stores
    __syncthreads();   // all s_sb/s_gb readers done
    #pragma unroll
    for (int nt = 0; nt < 4; ++nt) {
      int n = ncol + nt * 16 + cl;
      #pragma unroll
      for (int r = 0; r < 4; ++r)
        s_sb[(mrow + kg * 4 + r) * 136 + n] = f2bf(nh_sv[nt][r]);
    }
    __syncthreads();
    f32x4 pacc[4];
    #pragma unroll
    for (int nt = 0; nt < 4; ++nt) pacc[nt] = (f32x4){0.f, 0.f, 0.f, 0.f};
    #pragma unroll
    for (int ks = 0; ks < 4; ++ks) {
      bf16x8 ah = *reinterpret_cast<const bf16x8*>(s_sb + (mrow + cl) * 136 + ks * 32 + kg * 8);
      #pragma unroll
      for (int nt = 0; nt < 4; ++nt) {
        bf16x8 b = *reinterpret_cast<const bf16x8*>(Ur + (size_t)(ncol + nt * 16 + cl) * 128 + ks * 32 + kg * 8);
        pacc[nt] = __builtin_amdgcn_mfma_f32_16x16x32_bf16(ah, b, pacc[nt], 0, 0, 0);
      }
    }
    #pragma unroll
    for (int nt = 0; nt < 4; ++nt) {
      int n = ncol + nt * 16 + cl;
      #pragma unroll
      for (int r = 0; r < 4; ++r)
        s_gb[(mrow + kg * 4 + r) * 136 + n] = f2bf(pacc[nt][r]);
    }
    __syncthreads();
    // coalesced H store (bf16, full 256B rows)
    #pragma unroll
    for (int it = 0; it < 2; ++it) {
      int slot = it * 256 + tid;
      int row = slot >> 4, seg = slot & 15;
      if (base + row < E)
        *reinterpret_cast<uint4*>(Hout + (size_t)(base + row) * 128 + seg * 8) =
            *reinterpret_cast<const uint4*>(s_sb + row * 136 + seg * 8);
    }
    // coalesced Pf store (fp8, full 128B rows), encode from staged bf16
    #pragma unroll
    for (int it = 0; it < 4; ++it) {
      int slot = it * 256 + tid;
      int row = slot >> 5, cg = slot & 31;
      if (base + row < E) {
        uint2 pv = *reinterpret_cast<const uint2*>(s_gb + row * 136 + cg * 4);
        float p0 = ubits(pv.x << 16), p1 = ubits(pv.x & 0xffff0000u);
        float p2 = ubits(pv.y << 16), p3 = ubits(pv.y & 0xffff0000u);
        *reinterpret_cast<u32t*>(Pout + (size_t)(base + row) * 128 + cg * 4) =
            f32x4_to_fp8(p0, p1, p2, p3);
      }
    }
  }
}

extern "C" void kernel_launch(void* const* d_in, const int* in_sizes, int n_in,
                              void* d_out, int out_size, void* d_ws, size_t ws_size,
                              hipStream_t stream) {
  const float* fmess = (const float*)d_in[0];
  const int*   bg    = (const int*)d_in[1];
  const float* Wz    = (const float*)d_in[2];
  const float* bz    = (const float*)d_in[3];
  const float* Wrw   = (const float*)d_in[4];
  const float* Urw   = (const float*)d_in[5];
  const float* urb   = (const float*)d_in[6];
  const float* Wh    = (const float*)d_in[7];
  const float* bh    = (const float*)d_in[8];
  float* out = (float*)d_out;

  const int E = in_sizes[0] / 128;
  const size_t EH = (size_t)E * 128;
  const size_t wshorts = 6 * 16384;

  // ws: H_A (EH u16) | Pf_A (EH u8) | fmb (EH u16) | bg32 (E*8 int) | wbf | flag
  u16t* HA   = (u16t*)d_ws;
  u8t*  PA   = (u8t*)(HA + EH);
  u16t* fmb  = (u16t*)(PA + EH);
  int*  bg32 = (int*)(fmb + EH);
  short* wbf = (short*)(bg32 + (size_t)E * 8);
  int*  flag = (int*)(wbf + wshorts);
  // B-set lives in d_out (dead before the final fp32 write)
  u16t* HB = (u16t*)d_out;
  u8t*  PB = (u8t*)(HB + EH);

  conv_weights<<<384, 256, 0, stream>>>(Wz, Wrw, Urw, Wh, wbf);
  detect64<<<1, 64, 0, stream>>>(bg, flag);
  compact_bg<<<(E * 8 + 255) / 256, 256, 0, stream>>>(bg, flag, bg32, E * 8);
  conv_fmess<<<(int)((EH / 8 + 255) / 256), 256, 0, stream>>>(fmess, fmb, EH / 8);

  const int grid = (E + 31) / 32;
  // s0 -> B ; s1 B->A ; s2 A->B ; s3 B->A ; s4 A -> fp32 out
  step_k<0><<<grid, 256, 0, stream>>>(fmb, bg32, nullptr, nullptr, wbf, bz, urb, bh, HB, PB, nullptr, E);
  step_k<1><<<grid, 256, 0, stream>>>(fmb, bg32, HB, PB, wbf, bz, urb, bh, HA, PA, nullptr, E);
  step_k<1><<<grid, 256, 0, stream>>>(fmb, bg32, HA, PA, wbf, bz, urb, bh, HB, PB, nullptr, E);
  step_k<1><<<grid, 256, 0, stream>>>(fmb, bg32, HB, PB, wbf, bz, urb, bh, HA, PA, nullptr, E);
  step_k<2><<<grid, 256, 0, stream>>>(fmb, bg32, HA, PA, wbf, bz, urb, bh, nullptr, nullptr, out, E);
}

// Round 8
// 776.500 us; speedup vs baseline: 1.4575x; 1.4575x over previous
//
#include <hip/hip_runtime.h>
#include <cstddef>
#include <cstdint>

typedef __attribute__((ext_vector_type(8))) short bf16x8;
typedef __attribute__((ext_vector_type(4))) float f32x4;
typedef __attribute__((ext_vector_type(2))) float f32x2;
typedef unsigned int u32t;
typedef unsigned short u16t;
typedef unsigned char u8t;

__device__ inline u16t f2bf(float f) {
  union { float f; unsigned u; } c; c.f = f;
  return (u16t)((c.u + 0x7FFFu + ((c.u >> 16) & 1u)) >> 16);
}
__device__ inline float ubits(u32t u) { union { u32t u; float f; } c; c.u = u; return c.f; }
__device__ inline float bf2f(u16t u) { return ubits(((u32t)u) << 16); }
__device__ inline float fsig(float x) { return __builtin_amdgcn_rcpf(1.f + __expf(-x)); }
__device__ inline float ftanh(float x) {
  float t = __expf(-2.f * fabsf(x));
  return copysignf((1.f - t) * __builtin_amdgcn_rcpf(1.f + t), x);
}
__device__ inline u32t f32x4_to_fp8(float a, float b, float c, float d) {
  int v = __builtin_amdgcn_cvt_pk_fp8_f32(a, b, 0, false);
  v = __builtin_amdgcn_cvt_pk_fp8_f32(c, d, v, true);
  return (u32t)v;
}

// bf16 weight mats, row-major [128][128]:
// 0: Wzf  1: Wzh  2: Wr  3: Whf  4: Whh  5: Ur
__global__ __launch_bounds__(256) void conv_weights(
    const float* __restrict__ Wz, const float* __restrict__ Wr,
    const float* __restrict__ Ur, const float* __restrict__ Wh,
    short* __restrict__ out)
{
  int i = blockIdx.x * 256 + threadIdx.x;
  if (i >= 6 * 16384) return;
  int mat = i >> 14, idx = i & 16383;
  int o = idx >> 7, c = idx & 127;
  float v = 0.f;
  switch (mat) {
    case 0: v = Wz[o * 256 + c];        break;
    case 1: v = Wz[o * 256 + 128 + c];  break;
    case 2: v = Wr[o * 128 + c];        break;
    case 3: v = Wh[o * 256 + c];        break;
    case 4: v = Wh[o * 256 + 128 + c];  break;
    case 5: v = Ur[o * 128 + c];        break;
  }
  out[i] = (short)f2bf(v);
}

__global__ __launch_bounds__(256) void conv_fmess(const float* __restrict__ src,
                                                  u16t* __restrict__ dst, size_t n8)
{
  size_t i = (size_t)blockIdx.x * 256 + threadIdx.x;
  if (i >= n8) return;
  const float4 a = *reinterpret_cast<const float4*>(src + i * 8);
  const float4 b = *reinterpret_cast<const float4*>(src + i * 8 + 4);
  uint4 o;
  o.x = ((u32t)f2bf(a.y) << 16) | f2bf(a.x);
  o.y = ((u32t)f2bf(a.w) << 16) | f2bf(a.z);
  o.z = ((u32t)f2bf(b.y) << 16) | f2bf(b.x);
  o.w = ((u32t)f2bf(b.w) << 16) | f2bf(b.z);
  *reinterpret_cast<uint4*>(dst + i * 8) = o;
}

__global__ void detect64(const int* __restrict__ bg, int* __restrict__ flag) {
  int t = threadIdx.x;
  int v = bg[2 * t + 1];
  unsigned long long m = __ballot(v == 0);
  if (t == 0) *flag = (m == ~0ull) ? 1 : 0;
}

__global__ __launch_bounds__(256) void compact_bg(const int* __restrict__ bg,
                                                  const int* __restrict__ flag,
                                                  int* __restrict__ bg32, int n)
{
  int i = blockIdx.x * 256 + threadIdx.x;
  if (i < n) bg32[i] = (*flag) ? bg[2 * (size_t)i] : bg[i];
}

// ---- gather macros (R7-proven): half-wave owns rows; 2-deep reg pipeline ----
#define GLD(H0, H1, H2, H3, P0, P1, P2, P3, q, nbb) { \
  int i0_ = __shfl(idx_all, (hf * 4 + (q)) * 8 + (nbb) + 0); \
  int i1_ = __shfl(idx_all, (hf * 4 + (q)) * 8 + (nbb) + 1); \
  int i2_ = __shfl(idx_all, (hf * 4 + (q)) * 8 + (nbb) + 2); \
  int i3_ = __shfl(idx_all, (hf * 4 + (q)) * 8 + (nbb) + 3); \
  H0 = *reinterpret_cast<const uint2*>(Hin + (size_t)i0_ * 128 + l5 * 4); \
  H1 = *reinterpret_cast<const uint2*>(Hin + (size_t)i1_ * 128 + l5 * 4); \
  H2 = *reinterpret_cast<const uint2*>(Hin + (size_t)i2_ * 128 + l5 * 4); \
  H3 = *reinterpret_cast<const uint2*>(Hin + (size_t)i3_ * 128 + l5 * 4); \
  P0 = *reinterpret_cast<const u32t*>(Pin + (size_t)i0_ * 128 + l5 * 4); \
  P1 = *reinterpret_cast<const u32t*>(Pin + (size_t)i1_ * 128 + l5 * 4); \
  P2 = *reinterpret_cast<const u32t*>(Pin + (size_t)i2_ * 128 + l5 * 4); \
  P3 = *reinterpret_cast<const u32t*>(Pin + (size_t)i3_ * 128 + l5 * 4); \
}

#define PRN(HV, PW) { \
  f32x2 plo_ = __builtin_amdgcn_cvt_pk_f32_fp8((int)(PW), false); \
  f32x2 phi_ = __builtin_amdgcn_cvt_pk_f32_fp8((int)(PW), true); \
  float h0_ = ubits(HV.x << 16), h1_ = ubits(HV.x & 0xffff0000u); \
  float h2_ = ubits(HV.y << 16), h3_ = ubits(HV.y & 0xffff0000u); \
  s0 += h0_; g0 += fsig(r10 + plo_.x) * h0_; \
  s1 += h1_; g1 += fsig(r11 + plo_.y) * h1_; \
  s2 += h2_; g2 += fsig(r12 + phi_.x) * h2_; \
  s3 += h3_; g3 += fsig(r13 + phi_.y) * h3_; \
}

#define PR4(HH0, HH1, HH2, HH3, PP0, PP1, PP2, PP3) \
  PRN(HH0, PP0) PRN(HH1, PP1) PRN(HH2, PP2) PRN(HH3, PP3)

#define INITR(q) { \
  int rl_ = wave * 8 + hf * 4 + (q); \
  uint2 rp_ = *reinterpret_cast<const uint2*>(s_R1 + rl_ * 136 + l5 * 4); \
  r10 = ubits(rp_.x << 16); r11 = ubits(rp_.x & 0xffff0000u); \
  r12 = ubits(rp_.y << 16); r13 = ubits(rp_.y & 0xffff0000u); \
  s0 = s1 = s2 = s3 = 0.f; g0 = g1 = g2 = g3 = 0.f; \
}

#define FINR(q) { \
  int rl_ = wave * 8 + hf * 4 + (q); \
  uint2 sp_, gp_; \
  sp_.x = ((u32t)f2bf(s1) << 16) | f2bf(s0); \
  sp_.y = ((u32t)f2bf(s3) << 16) | f2bf(s2); \
  gp_.x = ((u32t)f2bf(g1) << 16) | f2bf(g0); \
  gp_.y = ((u32t)f2bf(g3) << 16) | f2bf(g2); \
  *reinterpret_cast<uint2*>(s_sb + rl_ * 136 + l5 * 4) = sp_; \
  *reinterpret_cast<uint2*>(s_gb + rl_ * 136 + l5 * 4) = gp_; \
}

// M=64 rows/block, 512 threads (8 waves = 2 rowgroups x 4 colgroups, 2 row-tiles/wave).
// LDS 52224 B: s_R1 @0 (also z-stash), s_sb @17408, s_gb @34816 (all u16[64][136]).
// MODE2 fp32 out-stage (stride 132) aliases s_sb+s_gb.
template<int MODE>   // 0=first step (h=0), 1=middle, 2=last (fp32 out)
__global__ __launch_bounds__(512, 4) void step_k(
    const u16t* __restrict__ fmb,
    const int*  __restrict__ bg32,
    const u16t* __restrict__ Hin,
    const u8t*  __restrict__ Pin,
    const short* __restrict__ wbf,
    const float* __restrict__ bz, const float* __restrict__ urb, const float* __restrict__ bh,
    u16t* __restrict__ Hout, u8t* __restrict__ Pout, float* __restrict__ houtf, int E)
{
  __shared__ __align__(16) char smem[52224];
  u16t* s_R1 = (u16t*)smem;
  u16t* s_sb = (u16t*)(smem + 17408);
  u16t* s_gb = (u16t*)(smem + 34816);

  const int tid = threadIdx.x, wave = tid >> 6, lane = tid & 63;
  const int cl = lane & 15, kg = lane >> 4;
  const int l5 = lane & 31, hf = lane >> 5;
  const int base = blockIdx.x * 64;
  const int wrow = (wave & 1) * 32, ncol = (wave >> 1) * 32;

  const short* Wzf = wbf;
  const short* Wzh = wbf + 16384;
  const short* Wr  = wbf + 2 * 16384;
  const short* Whf = wbf + 3 * 16384;
  const short* Whh = wbf + 4 * 16384;
  const short* Ur  = wbf + 5 * 16384;

  // af fragments straight from global (fmb tile is L2-hot), held in regs
  bf16x8 af[2][4];
  #pragma unroll
  for (int rt = 0; rt < 2; ++rt) {
    int ar = base + wrow + rt * 16 + cl;
    if (ar >= E) ar = E - 1;
    #pragma unroll
    for (int ks = 0; ks < 4; ++ks)
      af[rt][ks] = *reinterpret_cast<const bf16x8*>(fmb + (size_t)ar * 128 + ks * 32 + kg * 8);
  }

  int idx_all = 0;
  if (MODE != 0) {
    int er = base + wave * 8 + (lane >> 3);
    if (er >= E) er = 0;
    idx_all = bg32[(size_t)er * 8 + (lane & 7)];
  }

  if (MODE != 0) {
    // ---- R1 = fmess @ Wr^T + urb -> s_R1 ----
    f32x4 racc[2][2];
    #pragma unroll
    for (int rt = 0; rt < 2; ++rt)
      #pragma unroll
      for (int nt = 0; nt < 2; ++nt) racc[rt][nt] = (f32x4){0.f, 0.f, 0.f, 0.f};
    #pragma unroll
    for (int ks = 0; ks < 4; ++ks) {
      #pragma unroll
      for (int nt = 0; nt < 2; ++nt) {
        bf16x8 b = *reinterpret_cast<const bf16x8*>(Wr + (size_t)(ncol + nt * 16 + cl) * 128 + ks * 32 + kg * 8);
        #pragma unroll
        for (int rt = 0; rt < 2; ++rt)
          racc[rt][nt] = __builtin_amdgcn_mfma_f32_16x16x32_bf16(af[rt][ks], b, racc[rt][nt], 0, 0, 0);
      }
    }
    #pragma unroll
    for (int nt = 0; nt < 2; ++nt) {
      int n = ncol + nt * 16 + cl;
      float bias = urb[n];
      #pragma unroll
      for (int rt = 0; rt < 2; ++rt)
        #pragma unroll
        for (int r = 0; r < 4; ++r)
          s_R1[(wrow + rt * 16 + kg * 4 + r) * 136 + n] = f2bf(racc[rt][nt][r] + bias);
    }
    __syncthreads();

    // ---- gather: 8 rows per wave, 2-deep pipeline ----
    uint2 HA0, HA1, HA2, HA3, HB0, HB1, HB2, HB3;
    u32t  PA0, PA1, PA2, PA3, PB0, PB1, PB2, PB3;
    float s0, s1, s2, s3, g0, g1, g2, g3, r10, r11, r12, r13;

    GLD(HA0, HA1, HA2, HA3, PA0, PA1, PA2, PA3, 0, 0)
    GLD(HB0, HB1, HB2, HB3, PB0, PB1, PB2, PB3, 0, 4)
    INITR(0)
    PR4(HA0, HA1, HA2, HA3, PA0, PA1, PA2, PA3)
    GLD(HA0, HA1, HA2, HA3, PA0, PA1, PA2, PA3, 1, 0)
    PR4(HB0, HB1, HB2, HB3, PB0, PB1, PB2, PB3)
    FINR(0)
    GLD(HB0, HB1, HB2, HB3, PB0, PB1, PB2, PB3, 1, 4)
    INITR(1)
    PR4(HA0, HA1, HA2, HA3, PA0, PA1, PA2, PA3)
    GLD(HA0, HA1, HA2, HA3, PA0, PA1, PA2, PA3, 2, 0)
    PR4(HB0, HB1, HB2, HB3, PB0, PB1, PB2, PB3)
    FINR(1)
    GLD(HB0, HB1, HB2, HB3, PB0, PB1, PB2, PB3, 2, 4)
    INITR(2)
    PR4(HA0, HA1, HA2, HA3, PA0, PA1, PA2, PA3)
    GLD(HA0, HA1, HA2, HA3, PA0, PA1, PA2, PA3, 3, 0)
    PR4(HB0, HB1, HB2, HB3, PB0, PB1, PB2, PB3)
    FINR(2)
    GLD(HB0, HB1, HB2, HB3, PB0, PB1, PB2, PB3, 3, 4)
    INITR(3)
    PR4(HA0, HA1, HA2, HA3, PA0, PA1, PA2, PA3)
    PR4(HB0, HB1, HB2, HB3, PB0, PB1, PB2, PB3)
    FINR(3)
    __syncthreads();
  }

  // ---- 4a: z = sigmoid(af·Wzf + sum·Wzh + bz), stash bf16 into s_R1 ----
  {
    f32x4 acc[2][2];
    #pragma unroll
    for (int rt = 0; rt < 2; ++rt)
      #pragma unroll
      for (int nt = 0; nt < 2; ++nt) acc[rt][nt] = (f32x4){0.f, 0.f, 0.f, 0.f};
    #pragma unroll
    for (int ks = 0; ks < 4; ++ks) {
      bf16x8 as0, as1;
      if (MODE != 0) {
        as0 = *reinterpret_cast<const bf16x8*>(s_sb + (wrow + cl) * 136 + ks * 32 + kg * 8);
        as1 = *reinterpret_cast<const bf16x8*>(s_sb + (wrow + 16 + cl) * 136 + ks * 32 + kg * 8);
      }
      #pragma unroll
      for (int nt = 0; nt < 2; ++nt) {
        int n = ncol + nt * 16 + cl;
        bf16x8 b1 = *reinterpret_cast<const bf16x8*>(Wzf + (size_t)n * 128 + ks * 32 + kg * 8);
        acc[0][nt] = __builtin_amdgcn_mfma_f32_16x16x32_bf16(af[0][ks], b1, acc[0][nt], 0, 0, 0);
        acc[1][nt] = __builtin_amdgcn_mfma_f32_16x16x32_bf16(af[1][ks], b1, acc[1][nt], 0, 0, 0);
        if (MODE != 0) {
          bf16x8 b2 = *reinterpret_cast<const bf16x8*>(Wzh + (size_t)n * 128 + ks * 32 + kg * 8);
          acc[0][nt] = __builtin_amdgcn_mfma_f32_16x16x32_bf16(as0, b2, acc[0][nt], 0, 0, 0);
          acc[1][nt] = __builtin_amdgcn_mfma_f32_16x16x32_bf16(as1, b2, acc[1][nt], 0, 0, 0);
        }
      }
    }
    #pragma unroll
    for (int nt = 0; nt < 2; ++nt) {
      int n = ncol + nt * 16 + cl;
      float bzv = bz[n];
      #pragma unroll
      for (int rt = 0; rt < 2; ++rt)
        #pragma unroll
        for (int r = 0; r < 4; ++r)
          s_R1[(wrow + rt * 16 + kg * 4 + r) * 136 + n] = f2bf(fsig(acc[rt][nt][r] + bzv));
    }
  }

  // ---- 4b: pre = tanh(af·Whf + gated·Whh + bh); epilogue ----
  float nh_sv[2][2][4];
  {
    f32x4 acc[2][2];
    #pragma unroll
    for (int rt = 0; rt < 2; ++rt)
      #pragma unroll
      for (int nt = 0; nt < 2; ++nt) acc[rt][nt] = (f32x4){0.f, 0.f, 0.f, 0.f};
    #pragma unroll
    for (int ks = 0; ks < 4; ++ks) {
      bf16x8 ag0, ag1;
      if (MODE != 0) {
        ag0 = *reinterpret_cast<const bf16x8*>(s_gb + (wrow + cl) * 136 + ks * 32 + kg * 8);
        ag1 = *reinterpret_cast<const bf16x8*>(s_gb + (wrow + 16 + cl) * 136 + ks * 32 + kg * 8);
      }
      #pragma unroll
      for (int nt = 0; nt < 2; ++nt) {
        int n = ncol + nt * 16 + cl;
        bf16x8 b1 = *reinterpret_cast<const bf16x8*>(Whf + (size_t)n * 128 + ks * 32 + kg * 8);
        acc[0][nt] = __builtin_amdgcn_mfma_f32_16x16x32_bf16(af[0][ks], b1, acc[0][nt], 0, 0, 0);
        acc[1][nt] = __builtin_amdgcn_mfma_f32_16x16x32_bf16(af[1][ks], b1, acc[1][nt], 0, 0, 0);
        if (MODE != 0) {
          bf16x8 b2 = *reinterpret_cast<const bf16x8*>(Whh + (size_t)n * 128 + ks * 32 + kg * 8);
          acc[0][nt] = __builtin_amdgcn_mfma_f32_16x16x32_bf16(ag0, b2, acc[0][nt], 0, 0, 0);
          acc[1][nt] = __builtin_amdgcn_mfma_f32_16x16x32_bf16(ag1, b2, acc[1][nt], 0, 0, 0);
        }
      }
    }
    #pragma unroll
    for (int nt = 0; nt < 2; ++nt) {
      int n = ncol + nt * 16 + cl;
      float bhv = bh[n];
      #pragma unroll
      for (int rt = 0; rt < 2; ++rt)
        #pragma unroll
        for (int r = 0; r < 4; ++r) {
          int rowt = wrow + rt * 16 + kg * 4 + r;
          int e = base + rowt;
          float pre = ftanh(acc[rt][nt][r] + bhv);
          float z   = bf2f(s_R1[rowt * 136 + n]);
          float sh  = (MODE == 0) ? 0.f : bf2f(s_sb[rowt * 136 + n]);
          float nh  = (1.f - z) * sh + z * pre;
          if (e == 0) nh = 0.f;
          nh_sv[rt][nt][r] = nh;
        }
    }
  }

  // ---- outputs ----
  if (MODE == 2) {
    __syncthreads();
    float* so = (float*)(smem + 17408);   // stride 132 fp32, 64 rows
    #pragma unroll
    for (int nt = 0; nt < 2; ++nt) {
      int n = ncol + nt * 16 + cl;
      #pragma unroll
      for (int rt = 0; rt < 2; ++rt)
        #pragma unroll
        for (int r = 0; r < 4; ++r)
          so[(wrow + rt * 16 + kg * 4 + r) * 132 + n] = nh_sv[rt][nt][r];
    }
    __syncthreads();
    #pragma unroll
    for (int it = 0; it < 4; ++it) {
      int slot = it * 512 + tid;
      int row = slot >> 5, seg = slot & 31;
      if (base + row < E)
        *reinterpret_cast<float4*>(houtf + (size_t)(base + row) * 128 + seg * 4) =
            *reinterpret_cast<const float4*>(so + row * 132 + seg * 4);
    }
  } else {
    __syncthreads();   // all s_sb/s_gb readers done
    #pragma unroll
    for (int nt = 0; nt < 2; ++nt) {
      int n = ncol + nt * 16 + cl;
      #pragma unroll
      for (int rt = 0; rt < 2; ++rt)
        #pragma unroll
        for (int r = 0; r < 4; ++r)
          s_sb[(wrow + rt * 16 + kg * 4 + r) * 136 + n] = f2bf(nh_sv[rt][nt][r]);
    }
    __syncthreads();
    // P_next = h_next @ Ur^T -> s_gb (bf16)
    f32x4 pacc[2][2];
    #pragma unroll
    for (int rt = 0; rt < 2; ++rt)
      #pragma unroll
      for (int nt = 0; nt < 2; ++nt) pacc[rt][nt] = (f32x4){0.f, 0.f, 0.f, 0.f};
    #pragma unroll
    for (int ks = 0; ks < 4; ++ks) {
      bf16x8 ah0 = *reinterpret_cast<const bf16x8*>(s_sb + (wrow + cl) * 136 + ks * 32 + kg * 8);
      bf16x8 ah1 = *reinterpret_cast<const bf16x8*>(s_sb + (wrow + 16 + cl) * 136 + ks * 32 + kg * 8);
      #pragma unroll
      for (int nt = 0; nt < 2; ++nt) {
        bf16x8 b = *reinterpret_cast<const bf16x8*>(Ur + (size_t)(ncol + nt * 16 + cl) * 128 + ks * 32 + kg * 8);
        pacc[0][nt] = __builtin_amdgcn_mfma_f32_16x16x32_bf16(ah0, b, pacc[0][nt], 0, 0, 0);
        pacc[1][nt] = __builtin_amdgcn_mfma_f32_16x16x32_bf16(ah1, b, pacc[1][nt], 0, 0, 0);
      }
    }
    #pragma unroll
    for (int nt = 0; nt < 2; ++nt) {
      int n = ncol + nt * 16 + cl;
      #pragma unroll
      for (int rt = 0; rt < 2; ++rt)
        #pragma unroll
        for (int r = 0; r < 4; ++r)
          s_gb[(wrow + rt * 16 + kg * 4 + r) * 136 + n] = f2bf(pacc[rt][nt][r]);
    }
    __syncthreads();
    // coalesced H store (bf16 rows)
    #pragma unroll
    for (int it = 0; it < 2; ++it) {
      int slot = it * 512 + tid;
      int row = slot >> 4, seg = slot & 15;
      if (base + row < E)
        *reinterpret_cast<uint4*>(Hout + (size_t)(base + row) * 128 + seg * 8) =
            *reinterpret_cast<const uint4*>(s_sb + row * 136 + seg * 8);
    }
    // coalesced P store (fp8 rows)
    #pragma unroll
    for (int it = 0; it < 4; ++it) {
      int slot = it * 512 + tid;
      int row = slot >> 5, cg = slot & 31;
      if (base + row < E) {
        uint2 pv = *reinterpret_cast<const uint2*>(s_gb + row * 136 + cg * 4);
        float p0 = ubits(pv.x << 16), p1 = ubits(pv.x & 0xffff0000u);
        float p2 = ubits(pv.y << 16), p3 = ubits(pv.y & 0xffff0000u);
        *reinterpret_cast<u32t*>(Pout + (size_t)(base + row) * 128 + cg * 4) =
            f32x4_to_fp8(p0, p1, p2, p3);
      }
    }
  }
}

extern "C" void kernel_launch(void* const* d_in, const int* in_sizes, int n_in,
                              void* d_out, int out_size, void* d_ws, size_t ws_size,
                              hipStream_t stream) {
  const float* fmess = (const float*)d_in[0];
  const int*   bg    = (const int*)d_in[1];
  const float* Wz    = (const float*)d_in[2];
  const float* bz    = (const float*)d_in[3];
  const float* Wrw   = (const float*)d_in[4];
  const float* Urw   = (const float*)d_in[5];
  const float* urb   = (const float*)d_in[6];
  const float* Wh    = (const float*)d_in[7];
  const float* bh    = (const float*)d_in[8];
  float* out = (float*)d_out;

  const int E = in_sizes[0] / 128;
  const size_t EH = (size_t)E * 128;
  const size_t wshorts = 6 * 16384;

  // ws (~101 MB, proven): HA u16 | PA u8 | fmb u16 | bg32 int | wbf | flag
  u16t* HA   = (u16t*)d_ws;
  u8t*  PA   = (u8t*)(HA + EH);
  u16t* fmb  = (u16t*)(PA + EH);
  int*  bg32 = (int*)(fmb + EH);
  short* wbf = (short*)(bg32 + (size_t)E * 8);
  int*  flag = (int*)(wbf + wshorts);
  // B-set in d_out (dead before the final fp32 write)
  u16t* HB = (u16t*)d_out;
  u8t*  PB = (u8t*)(HB + EH);

  conv_weights<<<384, 256, 0, stream>>>(Wz, Wrw, Urw, Wh, wbf);
  detect64<<<1, 64, 0, stream>>>(bg, flag);
  compact_bg<<<(E * 8 + 255) / 256, 256, 0, stream>>>(bg, flag, bg32, E * 8);
  conv_fmess<<<(int)((EH / 8 + 255) / 256), 256, 0, stream>>>(fmess, fmb, EH / 8);

  const int grid = (E + 63) / 64;
  // s0 -> B ; s1 B->A ; s2 A->B ; s3 B->A ; s4 A -> fp32 out
  step_k<0><<<grid, 512, 0, stream>>>(fmb, bg32, nullptr, nullptr, wbf, bz, urb, bh, HB, PB, nullptr, E);
  step_k<1><<<grid, 512, 0, stream>>>(fmb, bg32, HB, PB, wbf, bz, urb, bh, HA, PA, nullptr, E);
  step_k<1><<<grid, 512, 0, stream>>>(fmb, bg32, HA, PA, wbf, bz, urb, bh, HB, PB, nullptr, E);
  step_k<1><<<grid, 512, 0, stream>>>(fmb, bg32, HB, PB, wbf, bz, urb, bh, HA, PA, nullptr, E);
  step_k<2><<<grid, 512, 0, stream>>>(fmb, bg32, HA, PA, wbf, bz, urb, bh, nullptr, nullptr, out, E);
}